// Round 11
// baseline (40.869 us; speedup 1.0000x reference)
//
#include <hip/hip_runtime.h>

#define N_BOX 5376
#define NQ4   1344          // N_BOX/4
#define NCAND 1024
#define MAXD  300
#define NTH   1024
#define NBLK  129           // block 0 = NMS, blocks 1..128 = mask (1 row each)
#define NPREP 16            // blocks 1..16 also prep 84 groups each
#define PGRP  84            // NQ4 / 16
#define NPRE  320           // candidates covered by precomputed pairwise masks
#define NPREB 5             // NPRE/64
#define RANK_TGT 768
#define FLOOR_B 2000        // bucket(0.25f)
#define SCORE_T 0.25f

#define HSZ   4160          // 4096 + 64 pad slots
#define HSLOT(b) ((b) + ((b) >> 6))   // bank-conflict-free scan stride (65 ints)

#define MAGIC1 0x13579BDFu  // 4 distinct bytes: uniform poison fill cannot match
#define MAGIC2 0x2468ACE1u

// workspace offsets (16B aligned where vector-accessed)
#define WS_DONE  0          // u32[2] NMS-done magic handshake
#define WS_PFLG  16         // u32[32] per-prep-block magic flag pairs
#define WS_RRCC  144        // float4[300] : 4800
#define WS_SEL   4944       // int[300]    : 1200
#define WS_SVAL  6144       // u32[5376]   : 21504
#define WS_CLS   27648      // u32[1344]   : 5376
#define WS_CBOX  33024      // float4[5376]: 86016

typedef unsigned long long u64;
typedef unsigned int u32;
typedef unsigned short u16;

// monotone score->bucket map, fine resolution in [0.5, 1)
__device__ __forceinline__ int bucket_of(u32 u) {
    if (u >= 0x3F800000u) return 4095;
    return (u < 0x3F000000u) ? (int)(u >> 19) : 2016 + (int)((u - 0x3F000000u) >> 12);
}

__device__ __forceinline__ u32 cloadA(const u32* p) {
    return __hip_atomic_load(p, __ATOMIC_ACQUIRE, __HIP_MEMORY_SCOPE_AGENT);
}
__device__ __forceinline__ u32 cload32(const u32* p) {
    return __hip_atomic_load(p, __ATOMIC_RELAXED, __HIP_MEMORY_SCOPE_AGENT);
}
__device__ __forceinline__ u64 cload64(const u64* p) {
    return __hip_atomic_load(p, __ATOMIC_RELAXED, __HIP_MEMORY_SCOPE_AGENT);
}

union SMem {
    struct {                                  // block 0 (NMS) view ~102 KB
        int hist[HSZ];
        u16 basecopy[4096];
        u64 keys[NCAND];
        float4 cbox[NCAND];
        float4 selbox[MAXD];
        float4 batchb[64];
        u32 svals[N_BOX];
        u32 sclsp[NQ4];
        float4 scbox[NPRE];
        float sarea[NPRE];
        u64 supr[NPREB][NPRE];
        u64 selw[NPREB];
    } n;
    struct {                                  // blocks 1..128 (mask) view ~48 KB
        float sco[MAXD * 32];
        float2 rl_c[MAXD];
        int rl_k[MAXD];
        float4 rc_all[MAXD];
        int sel_all[MAXD];
    } m;
};

__global__ __launch_bounds__(NTH) void k_fused(
        const float* __restrict__ boxes, const float* __restrict__ proto,
        float* __restrict__ out, char* __restrict__ ws)
{
    __shared__ SMem sm;
    __shared__ int thrvar, ncvar, scnt_s, rcount;

    const int bid = blockIdx.x, tid = threadIdx.x;

    u32*    done    = (u32*)(ws + WS_DONE);
    u32*    pflg    = (u32*)(ws + WS_PFLG);
    float4* ws_rrcc = (float4*)(ws + WS_RRCC);
    int*    ws_sel  = (int*)(ws + WS_SEL);
    u32*    ws_sval = (u32*)(ws + WS_SVAL);
    u32*    ws_cls  = (u32*)(ws + WS_CLS);
    float4* ws_cbox = (float4*)(ws + WS_CBOX);

    if (bid >= 1) {
        // ===== PREP (blocks 1..16): distribute the boxes rows 0-7 fetch =====
        if (bid <= NPREP) {
            const int p = bid - 1;
            if (tid < PGRP) {
                const int t = p * PGRP + tid;
                const float4* r0 = (const float4*)(boxes);
                const float4* r1 = (const float4*)(boxes + 1 * N_BOX);
                const float4* r2 = (const float4*)(boxes + 2 * N_BOX);
                const float4* r3 = (const float4*)(boxes + 3 * N_BOX);
                const float4* r4 = (const float4*)(boxes + 4 * N_BOX);
                const float4* r5 = (const float4*)(boxes + 5 * N_BOX);
                const float4* r6 = (const float4*)(boxes + 6 * N_BOX);
                const float4* r7 = (const float4*)(boxes + 7 * N_BOX);

                float4 a = r4[t], b = r5[t], c = r6[t], d = r7[t];
                uint4 sv; u32 pk; float s; int cl;
                s = a.x; cl = 0;
                if (b.x > s) { s = b.x; cl = 1; }
                if (c.x > s) { s = c.x; cl = 2; }
                if (d.x > s) { s = d.x; cl = 3; }
                sv.x = __float_as_uint(s); pk = (u32)cl;
                s = a.y; cl = 0;
                if (b.y > s) { s = b.y; cl = 1; }
                if (c.y > s) { s = c.y; cl = 2; }
                if (d.y > s) { s = d.y; cl = 3; }
                sv.y = __float_as_uint(s); pk |= (u32)cl << 8;
                s = a.z; cl = 0;
                if (b.z > s) { s = b.z; cl = 1; }
                if (c.z > s) { s = c.z; cl = 2; }
                if (d.z > s) { s = d.z; cl = 3; }
                sv.z = __float_as_uint(s); pk |= (u32)cl << 16;
                s = a.w; cl = 0;
                if (b.w > s) { s = b.w; cl = 1; }
                if (c.w > s) { s = c.w; cl = 2; }
                if (d.w > s) { s = d.w; cl = 3; }
                sv.w = __float_as_uint(s); pk |= (u32)cl << 24;
                ((uint4*)ws_sval)[t] = sv;
                ws_cls[t] = pk;

                float4 xs = r0[t], ys = r1[t], wv = r2[t], hs = r3[t];
                int n = t << 2;
                ws_cbox[n + 0] = make_float4(ys.x - 0.5f * hs.x, xs.x - 0.5f * wv.x,
                                             ys.x + 0.5f * hs.x, xs.x + 0.5f * wv.x);
                ws_cbox[n + 1] = make_float4(ys.y - 0.5f * hs.y, xs.y - 0.5f * wv.y,
                                             ys.y + 0.5f * hs.y, xs.y + 0.5f * wv.y);
                ws_cbox[n + 2] = make_float4(ys.z - 0.5f * hs.z, xs.z - 0.5f * wv.z,
                                             ys.z + 0.5f * hs.z, xs.z + 0.5f * wv.z);
                ws_cbox[n + 3] = make_float4(ys.w - 0.5f * hs.w, xs.w - 0.5f * wv.w,
                                             ys.w + 0.5f * hs.w, xs.w + 0.5f * wv.w);
            }
            __syncthreads();
            __threadfence();
            if (tid == 0) {
                __hip_atomic_store(&pflg[2 * p + 1], MAGIC2 - (u32)p,
                                   __ATOMIC_RELEASE, __HIP_MEMORY_SCOPE_AGENT);
                __hip_atomic_store(&pflg[2 * p], MAGIC1 + (u32)p,
                                   __ATOMIC_RELEASE, __HIP_MEMORY_SCOPE_AGENT);
            }
        }

        // ===== MASK BLOCKS: 1 row each; 2 active compute waves =====
        const int r = bid - 1;
        const float rf = (float)r;

        float pr[32];
        if (tid < 128) {                          // prefetch proto pixel (r, tid)
            const float4* q = (const float4*)(proto + (((size_t)(r << 7) + tid) << 5));
            #pragma unroll
            for (int j = 0; j < 8; ++j) {
                float4 v = q[j];
                pr[4 * j + 0] = v.x; pr[4 * j + 1] = v.y;
                pr[4 * j + 2] = v.z; pr[4 * j + 3] = v.w;
            }
        }

        // acquire-poll the double-magic flag (guaranteed refresh each poll)
        if (tid == 0) {
            for (;;) {
                if (cloadA(done) == MAGIC1 && cloadA(done + 1) == MAGIC2) break;
                __builtin_amdgcn_s_sleep(4);
            }
        }
        __syncthreads();

        // pull the 6 KB of NMS results -> LDS (ordered after acquire)
        if (tid < 600) {
            ((u64*)sm.m.rc_all)[tid] = cload64((const u64*)ws_rrcc + tid);
        } else if (tid >= 640 && tid < 640 + MAXD) {
            sm.m.sel_all[tid - 640] = (int)cload32((const u32*)ws_sel + (tid - 640));
        }
        __syncthreads();

        // ordered row filter (wave 0)
        if (tid < 64) {
            int base = 0;
            for (int strip = 0; strip < 5; ++strip) {
                int k = strip * 64 + tid;
                bool flag = false; float4 rc = make_float4(1.f, 0.f, 1.f, 0.f);
                if (k < MAXD) {
                    rc = sm.m.rc_all[k];
                    flag = (rc.x <= rf) && (rf <= rc.y);
                }
                u64 m = __ballot(flag);
                int pos = base + (int)__popcll(m & ((1ull << tid) - 1ull));
                if (flag) { sm.m.rl_c[pos] = make_float2(rc.z, rc.w); sm.m.rl_k[pos] = k; }
                base += (int)__popcll(m);
            }
            if (tid == 0) rcount = base;
        }
        __syncthreads();
        const int L = rcount;

        // stage surviving coeffs (all 1024 threads; gather from read-only boxes)
        for (int t = tid; t < L * 32; t += NTH) {
            int e = t >> 5, j = t & 31;
            int n = sm.m.sel_all[sm.m.rl_k[e]];
            n = (n < 0) ? 0 : n;
            sm.m.sco[t] = boxes[(8 + j) * N_BOX + n];
        }
        __syncthreads();

        if (tid < 128) {
            const float cf = (float)tid;
            float acc = 0.f;
            for (int e = 0; e < L; ++e) {
                float2 cc = sm.m.rl_c[e];
                if (cc.x <= cf && cf <= cc.y) {
                    const float* wv = &sm.m.sco[e << 5];
                    float d = 0.f;
                    #pragma unroll
                    for (int j = 0; j < 32; ++j) d = fmaf(pr[j], wv[j], d);
                    float sg = 1.f / (1.f + __expf(-d));
                    if (sg >= 0.5f) acc += sg;
                }
            }
            out[6 * MAXD + (r << 7) + tid] = acc;
        }
        return;
    }

    // ================= block 0: NMS (reads prep results, never touches boxes) ====
    // P0: zero (keys zero-init KEPT — safety net for any unwritten slot)
    for (int b = tid; b < HSZ; b += NTH) sm.n.hist[b] = 0;
    for (int i = tid; i < NCAND; i += NTH) sm.n.keys[i] = 0;
    if (tid == 0) { thrvar = FLOOR_B; ncvar = 0; }
    __syncthreads();

    // wait for all 16 prep blocks (poison-proof per-block magic pairs)
    if (tid < NPREP) {
        for (;;) {
            if (cloadA(&pflg[2 * tid]) == MAGIC1 + (u32)tid &&
                cloadA(&pflg[2 * tid + 1]) == MAGIC2 - (u32)tid) break;
            __builtin_amdgcn_s_sleep(1);
        }
    }
    __syncthreads();
    __threadfence();                              // acquire for the plain reads below

    // P1': prep scores/cls -> LDS (L3-hot, ~27 KB) + histogram
    for (int t = tid; t < NQ4; t += NTH) {
        uint4 sv = ((const uint4*)ws_sval)[t];
        ((uint4*)sm.n.svals)[t] = sv;
        sm.n.sclsp[t] = ws_cls[t];
        atomicAdd(&sm.n.hist[HSLOT(bucket_of(sv.x))], 1);
        atomicAdd(&sm.n.hist[HSLOT(bucket_of(sv.y))], 1);
        atomicAdd(&sm.n.hist[HSLOT(bucket_of(sv.z))], 1);
        atomicAdd(&sm.n.hist[HSLOT(bucket_of(sv.w))], 1);
    }
    __syncthreads();

    // P2+P3 (wave 0): threshold bucket + in-place suffix scan (conflict-free slots)
    if (tid < 64) {
        const int lane = tid;
        int csum = 0;
        for (int b = lane * 64; b < lane * 64 + 64; ++b) csum += sm.n.hist[HSLOT(b)];
        int incl = csum;
        for (int off = 1; off < 64; off <<= 1) {
            int t = __shfl_down(incl, off);
            if (lane + off < 64) incl += t;
        }
        int excl = __shfl_down(incl, 1);
        if (lane == 63) excl = 0;
        if (incl >= RANK_TGT && excl < RANK_TGT) {
            int cum = excl, thr = FLOOR_B;
            for (int b = lane * 64 + 63; b >= lane * 64; --b) {
                cum += sm.n.hist[HSLOT(b)];
                if (cum >= RANK_TGT) { thr = b; break; }
            }
            thrvar = (thr > FLOOR_B) ? thr : FLOOR_B;
        }
        int thr = thrvar;
        int run = excl;
        for (int b = lane * 64 + 63; b >= lane * 64; --b) {
            int h = sm.n.hist[HSLOT(b)];
            sm.n.hist[HSLOT(b)] = run;
            sm.n.basecopy[b] = (u16)run;
            if (b == thr) { int v = run + h; ncvar = (v < NCAND) ? v : NCAND; }
            run += h;
        }
    }
    __syncthreads();
    const int thr = thrvar;

    // P4: scatter candidates; coords gathered from L3-hot ws_cbox
    for (int t = tid; t < NQ4; t += NTH) {
        uint4 sv = ((const uint4*)sm.n.svals)[t];
        int b0 = bucket_of(sv.x), b1 = bucket_of(sv.y),
            b2 = bucket_of(sv.z), b3 = bucket_of(sv.w);
        int bm = max(max(b0, b1), max(b2, b3));
        if (bm < thr) continue;
        u32 pk = sm.n.sclsp[t];
        int n = t << 2;
        if (b0 >= thr) {
            int pos = atomicAdd(&sm.n.hist[HSLOT(b0)], 1);
            if (pos < NCAND) {
                sm.n.cbox[pos] = ws_cbox[n + 0];
                sm.n.keys[pos] = ((u64)sv.x << 25) | ((u64)(8191 - n) << 12)
                               | ((u64)(pk & 3u) << 10) | (u64)pos;
            }
        }
        if (b1 >= thr) {
            int pos = atomicAdd(&sm.n.hist[HSLOT(b1)], 1);
            if (pos < NCAND) {
                sm.n.cbox[pos] = ws_cbox[n + 1];
                sm.n.keys[pos] = ((u64)sv.y << 25) | ((u64)(8191 - (n + 1)) << 12)
                               | ((u64)((pk >> 8) & 3u) << 10) | (u64)pos;
            }
        }
        if (b2 >= thr) {
            int pos = atomicAdd(&sm.n.hist[HSLOT(b2)], 1);
            if (pos < NCAND) {
                sm.n.cbox[pos] = ws_cbox[n + 2];
                sm.n.keys[pos] = ((u64)sv.z << 25) | ((u64)(8191 - (n + 2)) << 12)
                               | ((u64)((pk >> 16) & 3u) << 10) | (u64)pos;
            }
        }
        if (b3 >= thr) {
            int pos = atomicAdd(&sm.n.hist[HSLOT(b3)], 1);
            if (pos < NCAND) {
                sm.n.cbox[pos] = ws_cbox[n + 3];
                sm.n.keys[pos] = ((u64)sv.w << 25) | ((u64)(8191 - (n + 3)) << 12)
                               | ((u64)((pk >> 24) & 3u) << 10) | (u64)pos;
            }
        }
    }
    __syncthreads();
    const int nc = ncvar;

    // P5: stabilize each bucket segment (deterministic exact-rank rewrite)
    {
        u64 myk[2]; int mypos[2]; int cnt = 0;
        for (int p = tid; p < nc; p += NTH) {
            u64 kp = sm.n.keys[p];
            int b = bucket_of((u32)(kp >> 25));
            int start = (int)sm.n.basecopy[b];
            int end = sm.n.hist[HSLOT(b)]; if (end > NCAND) end = NCAND;
            int rank = 0;
            for (int q = start; q < end; ++q) rank += (sm.n.keys[q] > kp);
            myk[cnt] = kp; mypos[cnt] = start + rank; ++cnt;
        }
        __syncthreads();
        for (int i = 0; i < cnt; ++i) sm.n.keys[mypos[i]] = myk[i];
    }
    __syncthreads();

    // P5b: sorted-order box/area tables for first NPRE candidates
    {
        const int lim = (nc < NPRE) ? nc : NPRE;
        for (int c = tid; c < NPRE; c += NTH) {
            float4 bx = make_float4(0.f, 0.f, 0.f, 0.f);
            if (c < lim) bx = sm.n.cbox[(int)(sm.n.keys[c] & 0x3FFu)];
            sm.n.scbox[c] = bx;
            sm.n.sarea[c] = (bx.z - bx.x) * (bx.w - bx.y);
        }
    }
    // sentinel pre-fill of ws results (overwritten for chosen slots in P6)
    for (int s = tid; s < MAXD; s += NTH) {
        ws_sel[s] = -1;
        ws_rrcc[s] = make_float4(1.f, 0.f, 1.f, 0.f);
    }
    __syncthreads();

    // P5c: pairwise overlap bitmasks (all 16 waves parallel)
    {
        const int wav = tid >> 6, lane = tid & 63;
        for (int t = wav; t < 15; t += NTH / 64) {
            int w, cb;
            if (t < 5)       { w = 0; cb = t << 6; }
            else if (t < 9)  { w = 1; cb = (t - 4) << 6; }
            else if (t < 12) { w = 2; cb = (t - 7) << 6; }
            else if (t < 14) { w = 3; cb = (t - 9) << 6; }
            else             { w = 4; cb = 256; }
            float4 qb = sm.n.scbox[(w << 6) + lane];
            float qa = sm.n.sarea[(w << 6) + lane];
            for (int c = cb; c < cb + 64; ++c) {
                float4 bx = sm.n.scbox[c];
                float ar = sm.n.sarea[c];
                float iy1 = fmaxf(bx.x, qb.x), ix1 = fmaxf(bx.y, qb.y);
                float iy2 = fminf(bx.z, qb.z), ix2 = fminf(bx.w, qb.w);
                float inter = fmaxf(iy2 - iy1, 0.f) * fmaxf(ix2 - ix1, 0.f);
                bool h = (1.75f * inter > 0.75f * (ar + qa) + 7.5e-10f);
                u64 m = __ballot(h);
                if (lane == 0) sm.n.supr[w][c] = m;
            }
        }
    }
    __syncthreads();

    // P6 (wave 0): batch-parallel greedy NMS
    if (tid < 64) {
        const int lane = tid;
        const u64 laneb = 1ull << lane;
        int scount = 0;
        for (int base = 0; base < nc; base += 64) {
            const int bidx = base >> 6;
            const bool pre = (base + 64 <= NPRE);
            int idx = base + lane;
            u64 k = 0;
            if (idx < nc) k = sm.n.keys[idx];
            float sc = __uint_as_float((u32)(k >> 25));
            bool valid = (idx < nc) && (sc >= SCORE_T);
            float4 bx = make_float4(0.f, 0.f, 0.f, 0.f);
            bool dead = false;
            u64 M = 0;
            if (pre) {
                if (valid) bx = sm.n.scbox[idx];
                #pragma unroll
                for (int w = 0; w < NPREB; ++w)
                    if (w < bidx)
                        dead = dead || ((sm.n.supr[w][idx] & sm.n.selw[w]) != 0ull);
                M = sm.n.supr[bidx][idx] & (laneb - 1ull);
            } else {
                if (valid) bx = sm.n.cbox[(int)(k & 0x3FFu)];
                sm.n.batchb[lane] = bx;
                float ar = (bx.z - bx.x) * (bx.w - bx.y);
                #pragma unroll 4
                for (int j = 0; j < scount; ++j) {
                    float4 sb = sm.n.selbox[j];
                    float sar = (sb.z - sb.x) * (sb.w - sb.y);
                    float iy1 = fmaxf(bx.x, sb.x), ix1 = fmaxf(bx.y, sb.y);
                    float iy2 = fminf(bx.z, sb.z), ix2 = fminf(bx.w, sb.w);
                    float inter = fmaxf(iy2 - iy1, 0.f) * fmaxf(ix2 - ix1, 0.f);
                    dead = dead || (1.75f * inter > 0.75f * (ar + sar) + 7.5e-10f);
                }
                #pragma unroll 4
                for (int q = 0; q < 64; ++q) {
                    float4 sb = sm.n.batchb[q];
                    float sar = (sb.z - sb.x) * (sb.w - sb.y);
                    float iy1 = fmaxf(bx.x, sb.x), ix1 = fmaxf(bx.y, sb.y);
                    float iy2 = fminf(bx.z, sb.z), ix2 = fminf(bx.w, sb.w);
                    float inter = fmaxf(iy2 - iy1, 0.f) * fmaxf(ix2 - ix1, 0.f);
                    bool h = (1.75f * inter > 0.75f * (ar + sar) + 7.5e-10f) && (q < lane);
                    if (h) M |= (1ull << q);
                }
            }

            u64 vmask  = __ballot(valid);
            u64 deadm  = __ballot(dead);
            u64 alive0 = vmask & ~deadm;
            u64 sel    = alive0;
            u64 conf   = __ballot((M & alive0) != 0ull) & alive0;
            while (conf) {
                int f = (int)__ffsll((unsigned long long)conf) - 1;
                conf &= conf - 1ull;
                u64 Mf = ((u64)(u32)__shfl((int)(M >> 32), f) << 32)
                       | (u64)(u32)__shfl((int)(M & 0xFFFFFFFFull), f);
                if (Mf & sel) sel &= ~(1ull << f);
            }
            if (pre && lane == 0) sm.n.selw[bidx] = sel;

            int navail = MAXD - scount;
            int myrank = (int)__popcll(sel & (laneb - 1ull));
            bool chosen = ((sel & laneb) != 0ull) && (myrank < navail);
            if (chosen) {
                int slot = scount + myrank;
                sm.n.selbox[slot] = bx;
                out[slot]        = sc;
                out[MAXD + slot] = (float)((k >> 10) & 3u);
                ((float4*)(out + 2 * MAXD))[slot] = bx;
                ws_sel[slot] = 8191 - (int)((k >> 12) & 0x1FFFu);
                ws_rrcc[slot] = make_float4(0.25f * bx.x, 0.25f * bx.z,
                                            0.25f * bx.y, 0.25f * bx.w);
            }
            int nsel = (int)__popcll(sel);
            if (nsel > navail) nsel = navail;
            scount += nsel;
            if (scount >= MAXD) break;
            if (vmask != 0xFFFFFFFFFFFFFFFFull) break;
        }
        if (lane == 0) scnt_s = scount;
    }
    __syncthreads();

    // release immediately (ws sentinels were pre-filled; chosen slots written in P6)
    __threadfence();
    if (tid == 0) {
        __hip_atomic_store(done + 1, MAGIC2, __ATOMIC_RELEASE, __HIP_MEMORY_SCOPE_AGENT);
        __hip_atomic_store(done, MAGIC1, __ATOMIC_RELEASE, __HIP_MEMORY_SCOPE_AGENT);
    }

    // P7: fill remaining out slots (not handshake-gated)
    const int c0f = scnt_s;
    for (int s = c0f + tid; s < MAXD; s += NTH) {
        out[s] = 0.f; out[MAXD + s] = 0.f;
        ((float4*)(out + 2 * MAXD))[s] = make_float4(0.f, 0.f, 0.f, 0.f);
    }
}

extern "C" void kernel_launch(void* const* d_in, const int* in_sizes, int n_in,
                              void* d_out, int out_size, void* d_ws, size_t ws_size,
                              hipStream_t stream) {
    const float* boxes = (const float*)d_in[0];   // (40, 5376) f32, channel-major
    const float* proto = (const float*)d_in[1];   // (128,128,32) f32
    float* out = (float*)d_out;                   // 300 + 300 + 1200 + 16384 f32
    char* w = (char*)d_ws;

    hipLaunchKernelGGL(k_fused, dim3(NBLK), dim3(NTH), 0, stream,
                       boxes, proto, out, w);
}

// Round 12
// 36.535 us; speedup vs baseline: 1.1186x; 1.1186x over previous
//
#include <hip/hip_runtime.h>

#define N_BOX 5376
#define NQ4   1344          // N_BOX/4
#define NCAND 1024
#define MAXD  300
#define NTH   1024
#define NBLK  129           // block 0 = NMS, blocks 1..128 = mask (1 row each)
#define NPRE  384           // candidates covered by precomputed pairwise masks
#define NPREB 6             // NPRE/64
#define RANK_TGT 768
#define FLOOR_B 2000        // bucket(0.25f)
#define SCORE_T 0.25f

#define HSZ   4160          // 4096 + 64 pad slots
#define HSLOT(b) ((b) + ((b) >> 6))   // bank-conflict-free scan stride (65 ints)

#define MAGIC1 0x13579BDFu  // 4 distinct bytes: uniform poison fill cannot match
#define MAGIC2 0x2468ACE1u

// workspace offsets
#define WS_DONE  0          // u32[2] magic handshake (no memset needed)
#define WS_RRCC  16         // float4[300] : 4800
#define WS_SEL   4816       // int[300]    : 1200

typedef unsigned long long u64;
typedef unsigned int u32;
typedef unsigned short u16;

// monotone score->bucket map, fine resolution in [0.5, 1)
__device__ __forceinline__ int bucket_of(u32 u) {
    if (u >= 0x3F800000u) return 4095;
    return (u < 0x3F000000u) ? (int)(u >> 19) : 2016 + (int)((u - 0x3F000000u) >> 12);
}

__device__ __forceinline__ u32 cloadA(const u32* p) {
    return __hip_atomic_load(p, __ATOMIC_ACQUIRE, __HIP_MEMORY_SCOPE_AGENT);
}
__device__ __forceinline__ u32 cload32(const u32* p) {
    return __hip_atomic_load(p, __ATOMIC_RELAXED, __HIP_MEMORY_SCOPE_AGENT);
}
__device__ __forceinline__ u64 cload64(const u64* p) {
    return __hip_atomic_load(p, __ATOMIC_RELAXED, __HIP_MEMORY_SCOPE_AGENT);
}

union SMem {
    struct {                                  // block 0 (NMS) view ~106 KB
        int hist[HSZ];
        u16 basecopy[4096];
        u64 keys[NCAND];
        float4 cbox[NCAND];
        float4 selbox[MAXD];
        float4 batchb[64];
        u32 svals[N_BOX];
        u32 sclsp[NQ4];
        float4 scbox[NPRE];
        float sarea[NPRE];
        u64 supr[NPREB][NPRE];
        u64 selw[NPREB];
    } n;
    struct {                                  // blocks 1..128 (mask) view ~48 KB
        float sco[MAXD * 32];
        float2 rl_c[MAXD];
        int rl_k[MAXD];
        float4 rc_all[MAXD];
        int sel_all[MAXD];
    } m;
};

__global__ __launch_bounds__(NTH) void k_fused(
        const float* __restrict__ boxes, const float* __restrict__ proto,
        float* __restrict__ out, char* __restrict__ ws)
{
    __shared__ SMem sm;
    __shared__ int thrvar, ncvar, scnt_s, rcount;

    const int bid = blockIdx.x, tid = threadIdx.x;

    u32*    done    = (u32*)(ws + WS_DONE);
    float4* ws_rrcc = (float4*)(ws + WS_RRCC);
    int*    ws_sel  = (int*)(ws + WS_SEL);

    if (bid >= 1) {
        // ===== MASK BLOCKS: 1 row each; 2 active compute waves =====
        const int r = bid - 1;
        const float rf = (float)r;

        float pr[32];
        if (tid < 128) {                          // prefetch proto pixel (r, tid)
            const float4* q = (const float4*)(proto + (((size_t)(r << 7) + tid) << 5));
            #pragma unroll
            for (int j = 0; j < 8; ++j) {
                float4 v = q[j];
                pr[4 * j + 0] = v.x; pr[4 * j + 1] = v.y;
                pr[4 * j + 2] = v.z; pr[4 * j + 3] = v.w;
            }
        }

        // acquire-poll the double-magic flag (guaranteed refresh each poll)
        if (tid == 0) {
            for (;;) {
                if (cloadA(done) == MAGIC1 && cloadA(done + 1) == MAGIC2) break;
                __builtin_amdgcn_s_sleep(4);
            }
        }
        __syncthreads();

        // pull the 6 KB of NMS results -> LDS (ordered after acquire)
        if (tid < 600) {
            ((u64*)sm.m.rc_all)[tid] = cload64((const u64*)ws_rrcc + tid);
        } else if (tid >= 640 && tid < 640 + MAXD) {
            sm.m.sel_all[tid - 640] = (int)cload32((const u32*)ws_sel + (tid - 640));
        }
        __syncthreads();

        // ordered row filter (wave 0)
        if (tid < 64) {
            int base = 0;
            for (int strip = 0; strip < 5; ++strip) {
                int k = strip * 64 + tid;
                bool flag = false; float4 rc = make_float4(1.f, 0.f, 1.f, 0.f);
                if (k < MAXD) {
                    rc = sm.m.rc_all[k];
                    flag = (rc.x <= rf) && (rf <= rc.y);
                }
                u64 m = __ballot(flag);
                int pos = base + (int)__popcll(m & ((1ull << tid) - 1ull));
                if (flag) { sm.m.rl_c[pos] = make_float2(rc.z, rc.w); sm.m.rl_k[pos] = k; }
                base += (int)__popcll(m);
            }
            if (tid == 0) rcount = base;
        }
        __syncthreads();
        const int L = rcount;

        // stage surviving coeffs (all 1024 threads; gather from read-only boxes)
        for (int t = tid; t < L * 32; t += NTH) {
            int e = t >> 5, j = t & 31;
            int n = sm.m.sel_all[sm.m.rl_k[e]];
            n = (n < 0) ? 0 : n;
            sm.m.sco[t] = boxes[(8 + j) * N_BOX + n];
        }
        __syncthreads();

        if (tid < 128) {
            const float cf = (float)tid;
            float acc = 0.f;
            for (int e = 0; e < L; ++e) {
                float2 cc = sm.m.rl_c[e];
                if (cc.x <= cf && cf <= cc.y) {
                    const float* wv = &sm.m.sco[e << 5];
                    float d = 0.f;
                    #pragma unroll
                    for (int j = 0; j < 32; ++j) d = fmaf(pr[j], wv[j], d);
                    float sg = 1.f / (1.f + __expf(-d));
                    if (sg >= 0.5f) acc += sg;
                }
            }
            out[6 * MAXD + (r << 7) + tid] = acc;
        }
        return;
    }

    // ================= block 0: NMS =================
    const float4* r0 = (const float4*)(boxes);
    const float4* r1 = (const float4*)(boxes + 1 * N_BOX);
    const float4* r2 = (const float4*)(boxes + 2 * N_BOX);
    const float4* r3 = (const float4*)(boxes + 3 * N_BOX);
    const float4* r4 = (const float4*)(boxes + 4 * N_BOX);
    const float4* r5 = (const float4*)(boxes + 5 * N_BOX);
    const float4* r6 = (const float4*)(boxes + 6 * N_BOX);
    const float4* r7 = (const float4*)(boxes + 7 * N_BOX);

    const int t0 = tid, t1 = tid + NTH;
    const bool has1 = (t1 < NQ4);

    // hoisted global loads: issue BEFORE LDS zeroing so HBM fetch hides under it
    const float4 Z = make_float4(0.f, 0.f, 0.f, 0.f);
    float4 xs0 = r0[t0], ys0 = r1[t0], ww0 = r2[t0], hh0 = r3[t0];
    float4 e0 = r4[t0], f0 = r5[t0], g0 = r6[t0], h0 = r7[t0];
    float4 xs1 = Z, ys1 = Z, ww1 = Z, hh1 = Z;
    float4 e1 = Z, f1 = Z, g1 = Z, h1 = Z;
    if (has1) {
        xs1 = r0[t1]; ys1 = r1[t1]; ww1 = r2[t1]; hh1 = r3[t1];
        e1 = r4[t1]; f1 = r5[t1]; g1 = r6[t1]; h1 = r7[t1];
    }

    // P0: zero (keys zero-init KEPT — safety net for any unwritten slot)
    for (int b = tid; b < HSZ; b += NTH) sm.n.hist[b] = 0;
    for (int i = tid; i < NCAND; i += NTH) sm.n.keys[i] = 0;
    if (tid == 0) { thrvar = FLOOR_B; ncvar = 0; }
    __syncthreads();

    // P1: score+cls from registers; stage sv/pk in LDS; histogram
    auto p1_proc = [&](int t, float4 a, float4 b, float4 c, float4 d) {
        uint4 sv; u32 pk; float s; int cl;
        s = a.x; cl = 0;
        if (b.x > s) { s = b.x; cl = 1; }
        if (c.x > s) { s = c.x; cl = 2; }
        if (d.x > s) { s = d.x; cl = 3; }
        sv.x = __float_as_uint(s); pk = (u32)cl;
        s = a.y; cl = 0;
        if (b.y > s) { s = b.y; cl = 1; }
        if (c.y > s) { s = c.y; cl = 2; }
        if (d.y > s) { s = d.y; cl = 3; }
        sv.y = __float_as_uint(s); pk |= (u32)cl << 8;
        s = a.z; cl = 0;
        if (b.z > s) { s = b.z; cl = 1; }
        if (c.z > s) { s = c.z; cl = 2; }
        if (d.z > s) { s = d.z; cl = 3; }
        sv.z = __float_as_uint(s); pk |= (u32)cl << 16;
        s = a.w; cl = 0;
        if (b.w > s) { s = b.w; cl = 1; }
        if (c.w > s) { s = c.w; cl = 2; }
        if (d.w > s) { s = d.w; cl = 3; }
        sv.w = __float_as_uint(s); pk |= (u32)cl << 24;
        ((uint4*)sm.n.svals)[t] = sv;
        sm.n.sclsp[t] = pk;
        atomicAdd(&sm.n.hist[HSLOT(bucket_of(sv.x))], 1);
        atomicAdd(&sm.n.hist[HSLOT(bucket_of(sv.y))], 1);
        atomicAdd(&sm.n.hist[HSLOT(bucket_of(sv.z))], 1);
        atomicAdd(&sm.n.hist[HSLOT(bucket_of(sv.w))], 1);
    };
    p1_proc(t0, e0, f0, g0, h0);
    if (has1) p1_proc(t1, e1, f1, g1, h1);
    __syncthreads();

    // P2+P3 (wave 0): threshold bucket + in-place suffix scan (conflict-free slots)
    if (tid < 64) {
        const int lane = tid;
        int csum = 0;
        for (int b = lane * 64; b < lane * 64 + 64; ++b) csum += sm.n.hist[HSLOT(b)];
        int incl = csum;
        for (int off = 1; off < 64; off <<= 1) {
            int t = __shfl_down(incl, off);
            if (lane + off < 64) incl += t;
        }
        int excl = __shfl_down(incl, 1);
        if (lane == 63) excl = 0;
        if (incl >= RANK_TGT && excl < RANK_TGT) {
            int cum = excl, thr = FLOOR_B;
            for (int b = lane * 64 + 63; b >= lane * 64; --b) {
                cum += sm.n.hist[HSLOT(b)];
                if (cum >= RANK_TGT) { thr = b; break; }
            }
            thrvar = (thr > FLOOR_B) ? thr : FLOOR_B;
        }
        int thr = thrvar;
        int run = excl;
        for (int b = lane * 64 + 63; b >= lane * 64; --b) {
            int h = sm.n.hist[HSLOT(b)];
            sm.n.hist[HSLOT(b)] = run;
            sm.n.basecopy[b] = (u16)run;
            if (b == thr) { int v = run + h; ncvar = (v < NCAND) ? v : NCAND; }
            run += h;
        }
    }
    __syncthreads();
    const int thr = thrvar;

    // P4: scatter candidates; sv/pk from LDS, corners from registers
    auto p4_scat = [&](int t, float4 xs, float4 ys, float4 wsv, float4 hs) {
        uint4 sv = ((const uint4*)sm.n.svals)[t];
        int b0 = bucket_of(sv.x), b1 = bucket_of(sv.y),
            b2 = bucket_of(sv.z), b3 = bucket_of(sv.w);
        int bm = max(max(b0, b1), max(b2, b3));
        if (bm < thr) return;
        u32 pk = sm.n.sclsp[t];
        int n = t << 2;
        if (b0 >= thr) {
            int pos = atomicAdd(&sm.n.hist[HSLOT(b0)], 1);
            if (pos < NCAND) {
                sm.n.cbox[pos] = make_float4(ys.x - 0.5f * hs.x, xs.x - 0.5f * wsv.x,
                                             ys.x + 0.5f * hs.x, xs.x + 0.5f * wsv.x);
                sm.n.keys[pos] = ((u64)sv.x << 25) | ((u64)(8191 - n) << 12)
                               | ((u64)(pk & 3u) << 10) | (u64)pos;
            }
        }
        if (b1 >= thr) {
            int pos = atomicAdd(&sm.n.hist[HSLOT(b1)], 1);
            if (pos < NCAND) {
                sm.n.cbox[pos] = make_float4(ys.y - 0.5f * hs.y, xs.y - 0.5f * wsv.y,
                                             ys.y + 0.5f * hs.y, xs.y + 0.5f * wsv.y);
                sm.n.keys[pos] = ((u64)sv.y << 25) | ((u64)(8191 - (n + 1)) << 12)
                               | ((u64)((pk >> 8) & 3u) << 10) | (u64)pos;
            }
        }
        if (b2 >= thr) {
            int pos = atomicAdd(&sm.n.hist[HSLOT(b2)], 1);
            if (pos < NCAND) {
                sm.n.cbox[pos] = make_float4(ys.z - 0.5f * hs.z, xs.z - 0.5f * wsv.z,
                                             ys.z + 0.5f * hs.z, xs.z + 0.5f * wsv.z);
                sm.n.keys[pos] = ((u64)sv.z << 25) | ((u64)(8191 - (n + 2)) << 12)
                               | ((u64)((pk >> 16) & 3u) << 10) | (u64)pos;
            }
        }
        if (b3 >= thr) {
            int pos = atomicAdd(&sm.n.hist[HSLOT(b3)], 1);
            if (pos < NCAND) {
                sm.n.cbox[pos] = make_float4(ys.w - 0.5f * hs.w, xs.w - 0.5f * wsv.w,
                                             ys.w + 0.5f * hs.w, xs.w + 0.5f * wsv.w);
                sm.n.keys[pos] = ((u64)sv.w << 25) | ((u64)(8191 - (n + 3)) << 12)
                               | ((u64)((pk >> 24) & 3u) << 10) | (u64)pos;
            }
        }
    };
    p4_scat(t0, xs0, ys0, ww0, hh0);
    if (has1) p4_scat(t1, xs1, ys1, ww1, hh1);
    __syncthreads();
    const int nc = ncvar;

    // P5: stabilize each bucket segment (deterministic exact-rank rewrite)
    {
        u64 myk[2]; int mypos[2]; int cnt = 0;
        for (int p = tid; p < nc; p += NTH) {
            u64 kp = sm.n.keys[p];
            int b = bucket_of((u32)(kp >> 25));
            int start = (int)sm.n.basecopy[b];
            int end = sm.n.hist[HSLOT(b)]; if (end > NCAND) end = NCAND;
            int rank = 0;
            for (int q = start; q < end; ++q) rank += (sm.n.keys[q] > kp);
            myk[cnt] = kp; mypos[cnt] = start + rank; ++cnt;
        }
        __syncthreads();
        for (int i = 0; i < cnt; ++i) sm.n.keys[mypos[i]] = myk[i];
    }
    __syncthreads();

    // P5b: sorted-order box/area tables for first NPRE candidates
    {
        const int lim = (nc < NPRE) ? nc : NPRE;
        for (int c = tid; c < NPRE; c += NTH) {
            float4 bx = make_float4(0.f, 0.f, 0.f, 0.f);
            if (c < lim) bx = sm.n.cbox[(int)(sm.n.keys[c] & 0x3FFu)];
            sm.n.scbox[c] = bx;
            sm.n.sarea[c] = (bx.z - bx.x) * (bx.w - bx.y);
        }
    }
    // sentinel pre-fill of ws results (overwritten for chosen slots in P6)
    for (int s = tid; s < MAXD; s += NTH) {
        ws_sel[s] = -1;
        ws_rrcc[s] = make_float4(1.f, 0.f, 1.f, 0.f);
    }
    __syncthreads();

    // P5c: pairwise overlap bitmasks for 6 batches (21 triangle chunks, 16 waves)
    {
        const int wav = tid >> 6, lane = tid & 63;
        for (int t = wav; t < 21; t += NTH / 64) {
            int w, cb;
            if (t < 6)       { w = 0; cb = t << 6; }
            else if (t < 11) { w = 1; cb = (t - 5) << 6; }
            else if (t < 15) { w = 2; cb = (t - 9) << 6; }
            else if (t < 18) { w = 3; cb = (t - 12) << 6; }
            else if (t < 20) { w = 4; cb = (t - 14) << 6; }
            else             { w = 5; cb = 320; }
            float4 qb = sm.n.scbox[(w << 6) + lane];
            float qa = sm.n.sarea[(w << 6) + lane];
            for (int c = cb; c < cb + 64; ++c) {
                float4 bx = sm.n.scbox[c];
                float ar = sm.n.sarea[c];
                float iy1 = fmaxf(bx.x, qb.x), ix1 = fmaxf(bx.y, qb.y);
                float iy2 = fminf(bx.z, qb.z), ix2 = fminf(bx.w, qb.w);
                float inter = fmaxf(iy2 - iy1, 0.f) * fmaxf(ix2 - ix1, 0.f);
                bool h = (1.75f * inter > 0.75f * (ar + qa) + 7.5e-10f);
                u64 m = __ballot(h);
                if (lane == 0) sm.n.supr[w][c] = m;
            }
        }
    }
    __syncthreads();

    // P6 (wave 0): batch-parallel greedy NMS
    if (tid < 64) {
        const int lane = tid;
        const u64 laneb = 1ull << lane;
        int scount = 0;
        for (int base = 0; base < nc; base += 64) {
            const int bidx = base >> 6;
            const bool pre = (base + 64 <= NPRE);
            int idx = base + lane;
            u64 k = 0;
            if (idx < nc) k = sm.n.keys[idx];
            float sc = __uint_as_float((u32)(k >> 25));
            bool valid = (idx < nc) && (sc >= SCORE_T);
            float4 bx = make_float4(0.f, 0.f, 0.f, 0.f);
            bool dead = false;
            u64 M = 0;
            if (pre) {
                if (valid) bx = sm.n.scbox[idx];
                #pragma unroll
                for (int w = 0; w < NPREB; ++w)
                    if (w < bidx)
                        dead = dead || ((sm.n.supr[w][idx] & sm.n.selw[w]) != 0ull);
                M = sm.n.supr[bidx][idx] & (laneb - 1ull);
            } else {
                if (valid) bx = sm.n.cbox[(int)(k & 0x3FFu)];
                sm.n.batchb[lane] = bx;
                float ar = (bx.z - bx.x) * (bx.w - bx.y);
                #pragma unroll 4
                for (int j = 0; j < scount; ++j) {
                    float4 sb = sm.n.selbox[j];
                    float sar = (sb.z - sb.x) * (sb.w - sb.y);
                    float iy1 = fmaxf(bx.x, sb.x), ix1 = fmaxf(bx.y, sb.y);
                    float iy2 = fminf(bx.z, sb.z), ix2 = fminf(bx.w, sb.w);
                    float inter = fmaxf(iy2 - iy1, 0.f) * fmaxf(ix2 - ix1, 0.f);
                    dead = dead || (1.75f * inter > 0.75f * (ar + sar) + 7.5e-10f);
                }
                #pragma unroll 4
                for (int q = 0; q < 64; ++q) {
                    float4 sb = sm.n.batchb[q];
                    float sar = (sb.z - sb.x) * (sb.w - sb.y);
                    float iy1 = fmaxf(bx.x, sb.x), ix1 = fmaxf(bx.y, sb.y);
                    float iy2 = fminf(bx.z, sb.z), ix2 = fminf(bx.w, sb.w);
                    float inter = fmaxf(iy2 - iy1, 0.f) * fmaxf(ix2 - ix1, 0.f);
                    bool h = (1.75f * inter > 0.75f * (ar + sar) + 7.5e-10f) && (q < lane);
                    if (h) M |= (1ull << q);
                }
            }

            u64 vmask  = __ballot(valid);
            u64 deadm  = __ballot(dead);
            u64 alive0 = vmask & ~deadm;
            u64 sel    = alive0;
            u64 conf   = __ballot((M & alive0) != 0ull) & alive0;
            while (conf) {
                int f = (int)__ffsll((unsigned long long)conf) - 1;
                conf &= conf - 1ull;
                u64 Mf = ((u64)(u32)__shfl((int)(M >> 32), f) << 32)
                       | (u64)(u32)__shfl((int)(M & 0xFFFFFFFFull), f);
                if (Mf & sel) sel &= ~(1ull << f);
            }
            if (pre && lane == 0) sm.n.selw[bidx] = sel;

            int navail = MAXD - scount;
            int myrank = (int)__popcll(sel & (laneb - 1ull));
            bool chosen = ((sel & laneb) != 0ull) && (myrank < navail);
            if (chosen) {
                int slot = scount + myrank;
                sm.n.selbox[slot] = bx;
                out[slot]        = sc;
                out[MAXD + slot] = (float)((k >> 10) & 3u);
                ((float4*)(out + 2 * MAXD))[slot] = bx;
                ws_sel[slot] = 8191 - (int)((k >> 12) & 0x1FFFu);
                ws_rrcc[slot] = make_float4(0.25f * bx.x, 0.25f * bx.z,
                                            0.25f * bx.y, 0.25f * bx.w);
            }
            int nsel = (int)__popcll(sel);
            if (nsel > navail) nsel = navail;
            scount += nsel;
            if (scount >= MAXD) break;
            if (vmask != 0xFFFFFFFFFFFFFFFFull) break;
        }
        if (lane == 0) scnt_s = scount;
    }
    __syncthreads();

    // release immediately (ws sentinels were pre-filled; chosen slots written in P6)
    __threadfence();
    if (tid == 0) {
        __hip_atomic_store(done + 1, MAGIC2, __ATOMIC_RELEASE, __HIP_MEMORY_SCOPE_AGENT);
        __hip_atomic_store(done, MAGIC1, __ATOMIC_RELEASE, __HIP_MEMORY_SCOPE_AGENT);
    }

    // P7: fill remaining out slots (not handshake-gated)
    const int c0f = scnt_s;
    for (int s = c0f + tid; s < MAXD; s += NTH) {
        out[s] = 0.f; out[MAXD + s] = 0.f;
        ((float4*)(out + 2 * MAXD))[s] = make_float4(0.f, 0.f, 0.f, 0.f);
    }
}

extern "C" void kernel_launch(void* const* d_in, const int* in_sizes, int n_in,
                              void* d_out, int out_size, void* d_ws, size_t ws_size,
                              hipStream_t stream) {
    const float* boxes = (const float*)d_in[0];   // (40, 5376) f32, channel-major
    const float* proto = (const float*)d_in[1];   // (128,128,32) f32
    float* out = (float*)d_out;                   // 300 + 300 + 1200 + 16384 f32
    char* w = (char*)d_ws;

    hipLaunchKernelGGL(k_fused, dim3(NBLK), dim3(NTH), 0, stream,
                       boxes, proto, out, w);
}

// Round 13
// 31.921 us; speedup vs baseline: 1.2803x; 1.1445x over previous
//
#include <hip/hip_runtime.h>

#define N_BOX 5376
#define NQ4   1344          // N_BOX/4
#define NCAND 1024
#define MAXD  300
#define NTH   1024
#define NBLK  129           // block 0 = NMS, blocks 1..128 = mask (1 row each)
#define NPRE  320           // candidates covered by precomputed pairwise masks
#define NPREB 5             // NPRE/64
#define RANK_TGT 768
#define FLOOR_B 2000        // bucket(0.25f)
#define SCORE_T 0.25f

#define HSZ   4160          // 4096 + 64 pad slots
#define HSLOT(b) ((b) + ((b) >> 6))   // bank-conflict-free scan stride (65 ints)

#define MAGIC1 0x13579BDFu  // 4 distinct bytes: uniform poison fill cannot match
#define MAGIC2 0x2468ACE1u

// workspace offsets
#define WS_DONE  0          // u32[2] magic handshake (no memset needed)
#define WS_RRCC  16         // float4[300] : 4800
#define WS_SEL   4816       // int[300]    : 1200

typedef unsigned long long u64;
typedef unsigned int u32;
typedef unsigned short u16;

// monotone score->bucket map, fine resolution in [0.5, 1)
__device__ __forceinline__ int bucket_of(u32 u) {
    if (u >= 0x3F800000u) return 4095;
    return (u < 0x3F000000u) ? (int)(u >> 19) : 2016 + (int)((u - 0x3F000000u) >> 12);
}

__device__ __forceinline__ u32 cloadA(const u32* p) {
    return __hip_atomic_load(p, __ATOMIC_ACQUIRE, __HIP_MEMORY_SCOPE_AGENT);
}
__device__ __forceinline__ u32 cload32(const u32* p) {
    return __hip_atomic_load(p, __ATOMIC_RELAXED, __HIP_MEMORY_SCOPE_AGENT);
}
__device__ __forceinline__ u64 cload64(const u64* p) {
    return __hip_atomic_load(p, __ATOMIC_RELAXED, __HIP_MEMORY_SCOPE_AGENT);
}

union SMem {
    struct {                                  // block 0 (NMS) view ~102 KB
        int hist[HSZ];
        u16 basecopy[4096];
        u64 keys[NCAND];
        float4 cbox[NCAND];
        float4 selbox[MAXD];
        float4 batchb[64];
        u32 svals[N_BOX];
        u32 sclsp[NQ4];
        float4 scbox[NPRE];
        float sarea[NPRE];
        u64 supr[NPREB][NPRE];
        u64 selw[NPREB];
    } n;
    struct {                                  // blocks 1..128 (mask) view ~48 KB
        float sco[MAXD * 32];
        float2 rl_c[MAXD];
        int rl_k[MAXD];
        float4 rc_all[MAXD];
        int sel_all[MAXD];
    } m;
};

__global__ __launch_bounds__(NTH) void k_fused(
        const float* __restrict__ boxes, const float* __restrict__ proto,
        float* __restrict__ out, char* __restrict__ ws)
{
    __shared__ SMem sm;
    __shared__ int thrvar, ncvar, scnt_s, rcount;

    const int bid = blockIdx.x, tid = threadIdx.x;

    u32*    done    = (u32*)(ws + WS_DONE);
    float4* ws_rrcc = (float4*)(ws + WS_RRCC);
    int*    ws_sel  = (int*)(ws + WS_SEL);

    if (bid >= 1) {
        // ===== MASK BLOCKS: 1 row each; 2 active compute waves =====
        const int r = bid - 1;
        const float rf = (float)r;

        float pr[32];
        if (tid < 128) {                          // prefetch proto pixel (r, tid)
            const float4* q = (const float4*)(proto + (((size_t)(r << 7) + tid) << 5));
            #pragma unroll
            for (int j = 0; j < 8; ++j) {
                float4 v = q[j];
                pr[4 * j + 0] = v.x; pr[4 * j + 1] = v.y;
                pr[4 * j + 2] = v.z; pr[4 * j + 3] = v.w;
            }
        }

        // acquire-poll the double-magic flag (guaranteed refresh each poll)
        if (tid == 0) {
            for (;;) {
                if (cloadA(done) == MAGIC1 && cloadA(done + 1) == MAGIC2) break;
                __builtin_amdgcn_s_sleep(4);
            }
        }
        __syncthreads();

        // pull the 6 KB of NMS results -> LDS (ordered after acquire)
        if (tid < 600) {
            ((u64*)sm.m.rc_all)[tid] = cload64((const u64*)ws_rrcc + tid);
        } else if (tid >= 640 && tid < 640 + MAXD) {
            sm.m.sel_all[tid - 640] = (int)cload32((const u32*)ws_sel + (tid - 640));
        }
        __syncthreads();

        // ordered row filter (wave 0)
        if (tid < 64) {
            int base = 0;
            for (int strip = 0; strip < 5; ++strip) {
                int k = strip * 64 + tid;
                bool flag = false; float4 rc = make_float4(1.f, 0.f, 1.f, 0.f);
                if (k < MAXD) {
                    rc = sm.m.rc_all[k];
                    flag = (rc.x <= rf) && (rf <= rc.y);
                }
                u64 m = __ballot(flag);
                int pos = base + (int)__popcll(m & ((1ull << tid) - 1ull));
                if (flag) { sm.m.rl_c[pos] = make_float2(rc.z, rc.w); sm.m.rl_k[pos] = k; }
                base += (int)__popcll(m);
            }
            if (tid == 0) rcount = base;
        }
        __syncthreads();
        const int L = rcount;

        // stage surviving coeffs (all 1024 threads; gather from read-only boxes)
        for (int t = tid; t < L * 32; t += NTH) {
            int e = t >> 5, j = t & 31;
            int n = sm.m.sel_all[sm.m.rl_k[e]];
            n = (n < 0) ? 0 : n;
            sm.m.sco[t] = boxes[(8 + j) * N_BOX + n];
        }
        __syncthreads();

        if (tid < 128) {
            const float cf = (float)tid;
            float acc = 0.f;
            for (int e = 0; e < L; ++e) {
                float2 cc = sm.m.rl_c[e];
                if (cc.x <= cf && cf <= cc.y) {
                    const float* wv = &sm.m.sco[e << 5];
                    float d = 0.f;
                    #pragma unroll
                    for (int j = 0; j < 32; ++j) d = fmaf(pr[j], wv[j], d);
                    float sg = 1.f / (1.f + __expf(-d));
                    if (sg >= 0.5f) acc += sg;
                }
            }
            out[6 * MAXD + (r << 7) + tid] = acc;
        }
        return;
    }

    // ================= block 0: NMS =================
    // P0: zero
    for (int b = tid; b < HSZ; b += NTH) sm.n.hist[b] = 0;
    for (int i = tid; i < NCAND; i += NTH) sm.n.keys[i] = 0;
    if (tid == 0) { thrvar = FLOOR_B; ncvar = 0; }
    __syncthreads();

    // P1: vectorized score+cls compute, cache in LDS, histogram
    {
        const float4* r4 = (const float4*)(boxes + 4 * N_BOX);
        const float4* r5 = (const float4*)(boxes + 5 * N_BOX);
        const float4* r6 = (const float4*)(boxes + 6 * N_BOX);
        const float4* r7 = (const float4*)(boxes + 7 * N_BOX);
        for (int t = tid; t < NQ4; t += NTH) {
            float4 a = r4[t], b = r5[t], c = r6[t], d = r7[t];
            uint4 sv; u32 pk; float s; int cl;
            s = a.x; cl = 0;
            if (b.x > s) { s = b.x; cl = 1; }
            if (c.x > s) { s = c.x; cl = 2; }
            if (d.x > s) { s = d.x; cl = 3; }
            sv.x = __float_as_uint(s); pk = (u32)cl;
            s = a.y; cl = 0;
            if (b.y > s) { s = b.y; cl = 1; }
            if (c.y > s) { s = c.y; cl = 2; }
            if (d.y > s) { s = d.y; cl = 3; }
            sv.y = __float_as_uint(s); pk |= (u32)cl << 8;
            s = a.z; cl = 0;
            if (b.z > s) { s = b.z; cl = 1; }
            if (c.z > s) { s = c.z; cl = 2; }
            if (d.z > s) { s = d.z; cl = 3; }
            sv.z = __float_as_uint(s); pk |= (u32)cl << 16;
            s = a.w; cl = 0;
            if (b.w > s) { s = b.w; cl = 1; }
            if (c.w > s) { s = c.w; cl = 2; }
            if (d.w > s) { s = d.w; cl = 3; }
            sv.w = __float_as_uint(s); pk |= (u32)cl << 24;
            ((uint4*)sm.n.svals)[t] = sv;
            sm.n.sclsp[t] = pk;
            atomicAdd(&sm.n.hist[HSLOT(bucket_of(sv.x))], 1);
            atomicAdd(&sm.n.hist[HSLOT(bucket_of(sv.y))], 1);
            atomicAdd(&sm.n.hist[HSLOT(bucket_of(sv.z))], 1);
            atomicAdd(&sm.n.hist[HSLOT(bucket_of(sv.w))], 1);
        }
    }
    __syncthreads();

    // P2+P3 (wave 0): threshold bucket + in-place suffix scan (conflict-free slots)
    if (tid < 64) {
        const int lane = tid;
        int csum = 0;
        for (int b = lane * 64; b < lane * 64 + 64; ++b) csum += sm.n.hist[HSLOT(b)];
        int incl = csum;
        for (int off = 1; off < 64; off <<= 1) {
            int t = __shfl_down(incl, off);
            if (lane + off < 64) incl += t;
        }
        int excl = __shfl_down(incl, 1);
        if (lane == 63) excl = 0;
        if (incl >= RANK_TGT && excl < RANK_TGT) {
            int cum = excl, thr = FLOOR_B;
            for (int b = lane * 64 + 63; b >= lane * 64; --b) {
                cum += sm.n.hist[HSLOT(b)];
                if (cum >= RANK_TGT) { thr = b; break; }
            }
            thrvar = (thr > FLOOR_B) ? thr : FLOOR_B;
        }
        int thr = thrvar;
        int run = excl;
        for (int b = lane * 64 + 63; b >= lane * 64; --b) {
            int h = sm.n.hist[HSLOT(b)];
            sm.n.hist[HSLOT(b)] = run;
            sm.n.basecopy[b] = (u16)run;
            if (b == thr) { int v = run + h; ncvar = (v < NCAND) ? v : NCAND; }
            run += h;
        }
    }
    __syncthreads();
    const int thr = thrvar;

    // P4: scatter candidates; coords loaded only for passing groups
    {
        const float4* r0 = (const float4*)(boxes);
        const float4* r1 = (const float4*)(boxes + 1 * N_BOX);
        const float4* r2 = (const float4*)(boxes + 2 * N_BOX);
        const float4* r3 = (const float4*)(boxes + 3 * N_BOX);
        for (int t = tid; t < NQ4; t += NTH) {
            uint4 sv = ((const uint4*)sm.n.svals)[t];
            int b0 = bucket_of(sv.x), b1 = bucket_of(sv.y),
                b2 = bucket_of(sv.z), b3 = bucket_of(sv.w);
            int bm = max(max(b0, b1), max(b2, b3));
            if (bm < thr) continue;
            float4 xs = r0[t], ys = r1[t], wsv = r2[t], hs = r3[t];
            u32 pk = sm.n.sclsp[t];
            int n = t << 2;
            if (b0 >= thr) {
                int pos = atomicAdd(&sm.n.hist[HSLOT(b0)], 1);
                if (pos < NCAND) {
                    sm.n.cbox[pos] = make_float4(ys.x - 0.5f * hs.x, xs.x - 0.5f * wsv.x,
                                                 ys.x + 0.5f * hs.x, xs.x + 0.5f * wsv.x);
                    sm.n.keys[pos] = ((u64)sv.x << 25) | ((u64)(8191 - n) << 12)
                                   | ((u64)(pk & 3u) << 10) | (u64)pos;
                }
            }
            if (b1 >= thr) {
                int pos = atomicAdd(&sm.n.hist[HSLOT(b1)], 1);
                if (pos < NCAND) {
                    sm.n.cbox[pos] = make_float4(ys.y - 0.5f * hs.y, xs.y - 0.5f * wsv.y,
                                                 ys.y + 0.5f * hs.y, xs.y + 0.5f * wsv.y);
                    sm.n.keys[pos] = ((u64)sv.y << 25) | ((u64)(8191 - (n + 1)) << 12)
                                   | ((u64)((pk >> 8) & 3u) << 10) | (u64)pos;
                }
            }
            if (b2 >= thr) {
                int pos = atomicAdd(&sm.n.hist[HSLOT(b2)], 1);
                if (pos < NCAND) {
                    sm.n.cbox[pos] = make_float4(ys.z - 0.5f * hs.z, xs.z - 0.5f * wsv.z,
                                                 ys.z + 0.5f * hs.z, xs.z + 0.5f * wsv.z);
                    sm.n.keys[pos] = ((u64)sv.z << 25) | ((u64)(8191 - (n + 2)) << 12)
                                   | ((u64)((pk >> 16) & 3u) << 10) | (u64)pos;
                }
            }
            if (b3 >= thr) {
                int pos = atomicAdd(&sm.n.hist[HSLOT(b3)], 1);
                if (pos < NCAND) {
                    sm.n.cbox[pos] = make_float4(ys.w - 0.5f * hs.w, xs.w - 0.5f * wsv.w,
                                                 ys.w + 0.5f * hs.w, xs.w + 0.5f * wsv.w);
                    sm.n.keys[pos] = ((u64)sv.w << 25) | ((u64)(8191 - (n + 3)) << 12)
                                   | ((u64)((pk >> 24) & 3u) << 10) | (u64)pos;
                }
            }
        }
    }
    __syncthreads();
    const int nc = ncvar;

    // P5: stabilize each bucket segment (deterministic exact-rank rewrite)
    {
        u64 myk[2]; int mypos[2]; int cnt = 0;
        for (int p = tid; p < nc; p += NTH) {
            u64 kp = sm.n.keys[p];
            int b = bucket_of((u32)(kp >> 25));
            int start = (int)sm.n.basecopy[b];
            int end = sm.n.hist[HSLOT(b)]; if (end > NCAND) end = NCAND;
            int rank = 0;
            for (int q = start; q < end; ++q) rank += (sm.n.keys[q] > kp);
            myk[cnt] = kp; mypos[cnt] = start + rank; ++cnt;
        }
        __syncthreads();
        for (int i = 0; i < cnt; ++i) sm.n.keys[mypos[i]] = myk[i];
    }
    __syncthreads();

    // P5b: sorted-order box/area tables for first NPRE candidates
    {
        const int lim = (nc < NPRE) ? nc : NPRE;
        for (int c = tid; c < NPRE; c += NTH) {
            float4 bx = make_float4(0.f, 0.f, 0.f, 0.f);
            if (c < lim) bx = sm.n.cbox[(int)(sm.n.keys[c] & 0x3FFu)];
            sm.n.scbox[c] = bx;
            sm.n.sarea[c] = (bx.z - bx.x) * (bx.w - bx.y);
        }
    }
    // sentinel pre-fill of ws results (overwritten for chosen slots in P6)
    for (int s = tid; s < MAXD; s += NTH) {
        ws_sel[s] = -1;
        ws_rrcc[s] = make_float4(1.f, 0.f, 1.f, 0.f);
    }
    __syncthreads();

    // P5c: pairwise overlap bitmasks (all 16 waves parallel)
    {
        const int wav = tid >> 6, lane = tid & 63;
        for (int t = wav; t < 15; t += NTH / 64) {
            int w, cb;
            if (t < 5)       { w = 0; cb = t << 6; }
            else if (t < 9)  { w = 1; cb = (t - 4) << 6; }
            else if (t < 12) { w = 2; cb = (t - 7) << 6; }
            else if (t < 14) { w = 3; cb = (t - 9) << 6; }
            else             { w = 4; cb = 256; }
            float4 qb = sm.n.scbox[(w << 6) + lane];
            float qa = sm.n.sarea[(w << 6) + lane];
            for (int c = cb; c < cb + 64; ++c) {
                float4 bx = sm.n.scbox[c];
                float ar = sm.n.sarea[c];
                float iy1 = fmaxf(bx.x, qb.x), ix1 = fmaxf(bx.y, qb.y);
                float iy2 = fminf(bx.z, qb.z), ix2 = fminf(bx.w, qb.w);
                float inter = fmaxf(iy2 - iy1, 0.f) * fmaxf(ix2 - ix1, 0.f);
                bool h = (1.75f * inter > 0.75f * (ar + qa) + 7.5e-10f);
                u64 m = __ballot(h);
                if (lane == 0) sm.n.supr[w][c] = m;
            }
        }
    }
    __syncthreads();

    // P6 (wave 0): batch-parallel greedy NMS
    if (tid < 64) {
        const int lane = tid;
        const u64 laneb = 1ull << lane;
        int scount = 0;
        for (int base = 0; base < nc; base += 64) {
            const int bidx = base >> 6;
            const bool pre = (base + 64 <= NPRE);
            int idx = base + lane;
            u64 k = 0;
            if (idx < nc) k = sm.n.keys[idx];
            float sc = __uint_as_float((u32)(k >> 25));
            bool valid = (idx < nc) && (sc >= SCORE_T);
            float4 bx = make_float4(0.f, 0.f, 0.f, 0.f);
            bool dead = false;
            u64 M = 0;
            if (pre) {
                if (valid) bx = sm.n.scbox[idx];
                #pragma unroll
                for (int w = 0; w < NPREB; ++w)
                    if (w < bidx)
                        dead = dead || ((sm.n.supr[w][idx] & sm.n.selw[w]) != 0ull);
                M = sm.n.supr[bidx][idx] & (laneb - 1ull);
            } else {
                if (valid) bx = sm.n.cbox[(int)(k & 0x3FFu)];
                sm.n.batchb[lane] = bx;
                float ar = (bx.z - bx.x) * (bx.w - bx.y);
                #pragma unroll 4
                for (int j = 0; j < scount; ++j) {
                    float4 sb = sm.n.selbox[j];
                    float sar = (sb.z - sb.x) * (sb.w - sb.y);
                    float iy1 = fmaxf(bx.x, sb.x), ix1 = fmaxf(bx.y, sb.y);
                    float iy2 = fminf(bx.z, sb.z), ix2 = fminf(bx.w, sb.w);
                    float inter = fmaxf(iy2 - iy1, 0.f) * fmaxf(ix2 - ix1, 0.f);
                    dead = dead || (1.75f * inter > 0.75f * (ar + sar) + 7.5e-10f);
                }
                #pragma unroll 4
                for (int q = 0; q < 64; ++q) {
                    float4 sb = sm.n.batchb[q];
                    float sar = (sb.z - sb.x) * (sb.w - sb.y);
                    float iy1 = fmaxf(bx.x, sb.x), ix1 = fmaxf(bx.y, sb.y);
                    float iy2 = fminf(bx.z, sb.z), ix2 = fminf(bx.w, sb.w);
                    float inter = fmaxf(iy2 - iy1, 0.f) * fmaxf(ix2 - ix1, 0.f);
                    bool h = (1.75f * inter > 0.75f * (ar + sar) + 7.5e-10f) && (q < lane);
                    if (h) M |= (1ull << q);
                }
            }

            u64 vmask  = __ballot(valid);
            u64 deadm  = __ballot(dead);
            u64 alive0 = vmask & ~deadm;
            u64 sel    = alive0;
            u64 conf   = __ballot((M & alive0) != 0ull) & alive0;
            while (conf) {
                int f = (int)__ffsll((unsigned long long)conf) - 1;
                conf &= conf - 1ull;
                u64 Mf = ((u64)(u32)__shfl((int)(M >> 32), f) << 32)
                       | (u64)(u32)__shfl((int)(M & 0xFFFFFFFFull), f);
                if (Mf & sel) sel &= ~(1ull << f);
            }
            if (pre && lane == 0) sm.n.selw[bidx] = sel;

            int navail = MAXD - scount;
            int myrank = (int)__popcll(sel & (laneb - 1ull));
            bool chosen = ((sel & laneb) != 0ull) && (myrank < navail);
            if (chosen) {
                int slot = scount + myrank;
                sm.n.selbox[slot] = bx;
                out[slot]        = sc;
                out[MAXD + slot] = (float)((k >> 10) & 3u);
                ((float4*)(out + 2 * MAXD))[slot] = bx;
                ws_sel[slot] = 8191 - (int)((k >> 12) & 0x1FFFu);
                ws_rrcc[slot] = make_float4(0.25f * bx.x, 0.25f * bx.z,
                                            0.25f * bx.y, 0.25f * bx.w);
            }
            int nsel = (int)__popcll(sel);
            if (nsel > navail) nsel = navail;
            scount += nsel;
            if (scount >= MAXD) break;
            if (vmask != 0xFFFFFFFFFFFFFFFFull) break;
        }
        if (lane == 0) scnt_s = scount;
    }
    __syncthreads();

    // release immediately (ws sentinels were pre-filled; chosen slots written in P6)
    __threadfence();
    if (tid == 0) {
        __hip_atomic_store(done + 1, MAGIC2, __ATOMIC_RELEASE, __HIP_MEMORY_SCOPE_AGENT);
        __hip_atomic_store(done, MAGIC1, __ATOMIC_RELEASE, __HIP_MEMORY_SCOPE_AGENT);
    }

    // P7: fill remaining out slots (not handshake-gated)
    const int c0f = scnt_s;
    for (int s = c0f + tid; s < MAXD; s += NTH) {
        out[s] = 0.f; out[MAXD + s] = 0.f;
        ((float4*)(out + 2 * MAXD))[s] = make_float4(0.f, 0.f, 0.f, 0.f);
    }
}

extern "C" void kernel_launch(void* const* d_in, const int* in_sizes, int n_in,
                              void* d_out, int out_size, void* d_ws, size_t ws_size,
                              hipStream_t stream) {
    const float* boxes = (const float*)d_in[0];   // (40, 5376) f32, channel-major
    const float* proto = (const float*)d_in[1];   // (128,128,32) f32
    float* out = (float*)d_out;                   // 300 + 300 + 1200 + 16384 f32
    char* w = (char*)d_ws;

    hipLaunchKernelGGL(k_fused, dim3(NBLK), dim3(NTH), 0, stream,
                       boxes, proto, out, w);
}